// Round 3
// baseline (152.030 us; speedup 1.0000x reference)
//
#include <hip/hip_runtime.h>
#include <hip/hip_bf16.h>
#include <math.h>

#define ORDER  3
#define POINTS 16
#define NNODES 2048
#define D1 64
#define D2 32
#define POOL1 32
#define POOL2 8
#define LABELS 10
#define PBLK   32          // k_pool blocks (64 rows each)

// -------------------------------------------------------------------------
// Kernel 1: feats[o,p,i] = mean_j cos(wm[o,p] * adj[o,i,j])
// One wave (64 lanes) per (i, o). Written as ms[i][o*16+p].
// cos via pre-scaled weight (1/2pi), v_fract, v_cos_f32.
// -------------------------------------------------------------------------
__global__ __launch_bounds__(64) void k_feats(const float* __restrict__ adj,
                                              const float* __restrict__ wm,
                                              float* __restrict__ ms) {
    const int i    = blockIdx.x;   // node row
    const int o    = blockIdx.y;   // order
    const int lane = threadIdx.x;  // 0..63

    const float INV2PI = 0.15915494309189535f;
    float wr[POINTS];
#pragma unroll
    for (int p = 0; p < POINTS; ++p)
        wr[p] = wm[o * POINTS + p] * INV2PI;

    const float4* row4 =
        reinterpret_cast<const float4*>(adj + ((size_t)o * NNODES + (size_t)i) * NNODES);

    float acc[POINTS];
#pragma unroll
    for (int p = 0; p < POINTS; ++p) acc[p] = 0.0f;

#pragma unroll
    for (int c = 0; c < NNODES / (4 * 64); ++c) {   // 8 chunks
        float4 a4 = row4[c * 64 + lane];
        float av[4] = {a4.x, a4.y, a4.z, a4.w};
#pragma unroll
        for (int e = 0; e < 4; ++e) {
            float a = av[e];
#pragma unroll
            for (int p = 0; p < POINTS; ++p) {
                float r = __builtin_amdgcn_fractf(a * wr[p]);  // [0,1) revolutions
                acc[p] += __builtin_amdgcn_cosf(r);            // cos(2*pi*r)
            }
        }
    }

    // wave reduce each accumulator (xor butterfly over 64 lanes)
#pragma unroll
    for (int p = 0; p < POINTS; ++p) {
        float v = acc[p];
#pragma unroll
        for (int off = 32; off >= 1; off >>= 1)
            v += __shfl_xor(v, off, 64);
        acc[p] = v;
    }

    if (lane == 0) {
        float* out = ms + (size_t)i * (ORDER * POINTS) + o * POINTS;
        const float rn = 1.0f / (float)NNODES;
#pragma unroll
        for (int p = 0; p < POINTS; ++p)
            out[p] = acc[p] * rn;
    }
}

// -------------------------------------------------------------------------
// Kernel 2: cooperative blocked MLP. 64 blocks x 256 threads; 32 rows/block.
// 48 -> relu 64 -> relu 32 -> tanh 32 -> 8. Weights+activations in LDS.
// -------------------------------------------------------------------------
__global__ __launch_bounds__(256) void k_mlp(const float* __restrict__ ms,
                                             const float* __restrict__ w1,
                                             const float* __restrict__ b1,
                                             const float* __restrict__ w2,
                                             const float* __restrict__ b2,
                                             const float* __restrict__ p1,
                                             const float* __restrict__ pb1,
                                             const float* __restrict__ p2,
                                             const float* __restrict__ pb2,
                                             float* __restrict__ h2out,
                                             float* __restrict__ sout) {
    const int t  = threadIdx.x;       // 0..255
    const int r0 = blockIdx.x * 32;   // first row of this block

    __shared__ float lms[32 * 48];
    __shared__ float lw1[48 * D1];
    __shared__ float lh1[32 * D1];
    __shared__ float lw2[D1 * D2];
    __shared__ float lh2[32 * D2];
    __shared__ float lp1[D2 * POOL1];
    __shared__ float lav[32 * POOL1];
    __shared__ float lp2[POOL1 * POOL2];
    __shared__ float ls[32 * POOL2];
    __shared__ float lb1[D1], lb2[D2], lpb1[POOL1], lpb2[POOL2];

    for (int idx = t; idx < 32 * 48; idx += 256) lms[idx] = ms[(size_t)r0 * 48 + idx];
    for (int idx = t; idx < 48 * D1; idx += 256) lw1[idx] = w1[idx];
    for (int idx = t; idx < D1 * D2; idx += 256) lw2[idx] = w2[idx];
    for (int idx = t; idx < D2 * POOL1; idx += 256) lp1[idx] = p1[idx];
    if (t < POOL1 * POOL2) lp2[t] = p2[t];
    if (t < D1) lb1[t] = b1[t];
    if (t < D2) lb2[t] = b2[t];
    if (t < POOL1) lpb1[t] = pb1[t];
    if (t < POOL2) lpb2[t] = pb2[t];
    __syncthreads();

    // layer 1: [32 x 48] @ [48 x 64] -> relu
    {
        const int dim = t & 63;
        const int rg  = t >> 6;       // 0..3, 8 rows each
        float acc[8];
#pragma unroll
        for (int j = 0; j < 8; ++j) acc[j] = 0.0f;
#pragma unroll
        for (int k4 = 0; k4 < 12; ++k4) {
            const float wa = lw1[(k4 * 4 + 0) * D1 + dim];
            const float wb = lw1[(k4 * 4 + 1) * D1 + dim];
            const float wc = lw1[(k4 * 4 + 2) * D1 + dim];
            const float wd = lw1[(k4 * 4 + 3) * D1 + dim];
#pragma unroll
            for (int j = 0; j < 8; ++j) {
                const float4 m4 = *reinterpret_cast<const float4*>(&lms[(rg * 8 + j) * 48 + k4 * 4]);
                acc[j] = fmaf(m4.x, wa, fmaf(m4.y, wb, fmaf(m4.z, wc, fmaf(m4.w, wd, acc[j]))));
            }
        }
        const float bb = lb1[dim];
#pragma unroll
        for (int j = 0; j < 8; ++j)
            lh1[(rg * 8 + j) * D1 + dim] = fmaxf(acc[j] + bb, 0.0f);
    }
    __syncthreads();

    // layer 2: [32 x 64] @ [64 x 32] -> relu
    {
        const int dim = t & 31;
        const int rg  = t >> 5;       // 0..7, 4 rows each
        float acc[4] = {0.0f, 0.0f, 0.0f, 0.0f};
#pragma unroll
        for (int k4 = 0; k4 < 16; ++k4) {
            const float wa = lw2[(k4 * 4 + 0) * D2 + dim];
            const float wb = lw2[(k4 * 4 + 1) * D2 + dim];
            const float wc = lw2[(k4 * 4 + 2) * D2 + dim];
            const float wd = lw2[(k4 * 4 + 3) * D2 + dim];
#pragma unroll
            for (int j = 0; j < 4; ++j) {
                const float4 h4 = *reinterpret_cast<const float4*>(&lh1[(rg * 4 + j) * D1 + k4 * 4]);
                acc[j] = fmaf(h4.x, wa, fmaf(h4.y, wb, fmaf(h4.z, wc, fmaf(h4.w, wd, acc[j]))));
            }
        }
        const float bb = lb2[dim];
#pragma unroll
        for (int j = 0; j < 4; ++j)
            lh2[(rg * 4 + j) * D2 + dim] = fmaxf(acc[j] + bb, 0.0f);
    }
    __syncthreads();

    reinterpret_cast<float4*>(h2out)[(size_t)blockIdx.x * 256 + t] =
        reinterpret_cast<const float4*>(lh2)[t];

    // layer 3: [32 x 32] @ [32 x 32] -> tanh
    {
        const int dim = t & 31;
        const int rg  = t >> 5;
        float acc[4] = {0.0f, 0.0f, 0.0f, 0.0f};
#pragma unroll
        for (int k4 = 0; k4 < 8; ++k4) {
            const float wa = lp1[(k4 * 4 + 0) * POOL1 + dim];
            const float wb = lp1[(k4 * 4 + 1) * POOL1 + dim];
            const float wc = lp1[(k4 * 4 + 2) * POOL1 + dim];
            const float wd = lp1[(k4 * 4 + 3) * POOL1 + dim];
#pragma unroll
            for (int j = 0; j < 4; ++j) {
                const float4 h4 = *reinterpret_cast<const float4*>(&lh2[(rg * 4 + j) * D2 + k4 * 4]);
                acc[j] = fmaf(h4.x, wa, fmaf(h4.y, wb, fmaf(h4.z, wc, fmaf(h4.w, wd, acc[j]))));
            }
        }
        const float bb = lpb1[dim];
#pragma unroll
        for (int j = 0; j < 4; ++j)
            lav[(rg * 4 + j) * POOL1 + dim] = tanhf(acc[j] + bb);
    }
    __syncthreads();

    // layer 4: [32 x 32] @ [32 x 8]
    {
        const int row = t >> 3;
        const int c   = t & 7;
        float acc = lpb2[c];
#pragma unroll
        for (int k = 0; k < POOL1; ++k)
            acc = fmaf(lav[row * POOL1 + k], lp2[k * POOL2 + c], acc);
        ls[row * POOL2 + c] = acc;
    }
    __syncthreads();

    sout[(size_t)r0 * POOL2 + t] = ls[t];
}

// -------------------------------------------------------------------------
// Kernel 3 (rewritten): 32 blocks x 256 threads.
// Each block: (A) redundant column stats (max, sum-exp) over all 2048 rows,
// two coalesced passes; (B) deterministic partial pooled sum over its own
// 64 rows -> part[b][c*32+d]. Block 0 publishes rinv[8].
// -------------------------------------------------------------------------
__global__ __launch_bounds__(256) void k_pool(const float* __restrict__ sIn,
                                              const float* __restrict__ h2,
                                              float* __restrict__ part,
                                              float* __restrict__ rinvOut) {
    const int b = blockIdx.x;   // 0..31
    const int t = threadIdx.x;  // 0..255

    __shared__ float red[256];
    __shared__ float colmax[POOL2];
    __shared__ float colsum[POOL2];
    __shared__ float att_l[64 * POOL2];

    const int c  = t & 7;       // column
    const int rg = t >> 3;      // row group 0..31 (64 rows each)

    // pass 1: column max (coalesced: 256 consecutive floats per iteration)
    float pm = -1e30f;
    for (int j = 0; j < 64; ++j)
        pm = fmaxf(pm, sIn[(size_t)(rg * 64 + j) * POOL2 + c]);
    red[c * 32 + rg] = pm;
    __syncthreads();
    if (t < POOL2) {
        float m = red[t * 32];
#pragma unroll
        for (int k = 1; k < 32; ++k) m = fmaxf(m, red[t * 32 + k]);
        colmax[t] = m;
    }
    __syncthreads();

    // pass 2: column sum of exp
    const float mx = colmax[c];
    float ps = 0.0f;
    for (int j = 0; j < 64; ++j)
        ps += expf(sIn[(size_t)(rg * 64 + j) * POOL2 + c] - mx);
    red[c * 32 + rg] = ps;
    __syncthreads();
    if (t < POOL2) {
        float s = 0.0f;
#pragma unroll
        for (int k = 0; k < 32; ++k) s += red[t * 32 + k];
        colsum[t] = s;
        if (b == 0) rinvOut[t] = 1.0f / s;
    }
    __syncthreads();

    // (B) att for this block's own 64 rows
    for (int idx = t; idx < 64 * POOL2; idx += 256) {
        const int j  = idx >> 3;
        const int cc = idx & 7;
        att_l[idx] = expf(sIn[(size_t)(b * 64 + j) * POOL2 + cc] - colmax[cc]);
    }
    __syncthreads();

    // partial[c, d] = sum_{j<64} att[j, c] * h2[b*64+j, d]
    {
        const int c2 = t >> 5;  // 0..7
        const int d  = t & 31;  // 0..31
        float acc = 0.0f;
        for (int j = 0; j < 64; ++j)
            acc = fmaf(att_l[j * POOL2 + c2], h2[(size_t)(b * 64 + j) * D2 + d], acc);
        part[(size_t)b * 256 + t] = acc;   // unnormalized; rinv applied in k_logits
    }
}

// -------------------------------------------------------------------------
// Kernel 4: reduce partials -> g[256]; logits = g @ cw + cb; log_softmax.
// -------------------------------------------------------------------------
__global__ __launch_bounds__(640) void k_logits(const float* __restrict__ part,
                                                const float* __restrict__ rinv8,
                                                const float* __restrict__ cw,
                                                const float* __restrict__ cb,
                                                float* __restrict__ out) {
    const int l    = threadIdx.x >> 6;  // 0..9
    const int lane = threadIdx.x & 63;
    __shared__ float gs[256];
    __shared__ float lg[LABELS];

    if (threadIdx.x < 256) {
        float s = 0.0f;
#pragma unroll
        for (int b = 0; b < PBLK; ++b) s += part[(size_t)b * 256 + threadIdx.x];
        gs[threadIdx.x] = s * rinv8[threadIdx.x >> 5];
    }
    __syncthreads();

    float p = 0.0f;
    for (int k = lane; k < POOL2 * D2; k += 64)
        p = fmaf(gs[k], cw[(size_t)k * LABELS + l], p);
#pragma unroll
    for (int off = 32; off >= 1; off >>= 1)
        p += __shfl_xor(p, off, 64);
    if (lane == 0) lg[l] = p + cb[l];
    __syncthreads();
    if (threadIdx.x == 0) {
        float m = lg[0];
#pragma unroll
        for (int i = 1; i < LABELS; ++i) m = fmaxf(m, lg[i]);
        float se = 0.0f;
#pragma unroll
        for (int i = 0; i < LABELS; ++i) se += expf(lg[i] - m);
        const float lse = m + logf(se);
#pragma unroll
        for (int i = 0; i < LABELS; ++i) out[i] = lg[i] - lse;
    }
}

extern "C" void kernel_launch(void* const* d_in, const int* in_sizes, int n_in,
                              void* d_out, int out_size, void* d_ws, size_t ws_size,
                              hipStream_t stream) {
    const float* adj = (const float*)d_in[0];
    const float* wm  = (const float*)d_in[1];
    const float* w1  = (const float*)d_in[2];
    const float* b1  = (const float*)d_in[3];
    const float* w2  = (const float*)d_in[4];
    const float* b2  = (const float*)d_in[5];
    const float* p1  = (const float*)d_in[6];
    const float* pb1 = (const float*)d_in[7];
    const float* p2  = (const float*)d_in[8];
    const float* pb2 = (const float*)d_in[9];
    const float* cw  = (const float*)d_in[10];
    const float* cb  = (const float*)d_in[11];
    float* out = (float*)d_out;

    float* ws   = (float*)d_ws;
    float* ms   = ws;                                     // 2048*48
    float* h2   = ms + (size_t)NNODES * ORDER * POINTS;   // 2048*32
    float* sS   = h2 + (size_t)NNODES * D2;               // 2048*8
    float* part = sS + (size_t)NNODES * POOL2;            // 32*256
    float* rinv = part + (size_t)PBLK * 256;              // 8

    hipLaunchKernelGGL(k_feats, dim3(NNODES, ORDER), dim3(64), 0, stream, adj, wm, ms);
    hipLaunchKernelGGL(k_mlp, dim3(NNODES / 32), dim3(256), 0, stream,
                       ms, w1, b1, w2, b2, p1, pb1, p2, pb2, h2, sS);
    hipLaunchKernelGGL(k_pool, dim3(PBLK), dim3(256), 0, stream, sS, h2, part, rinv);
    hipLaunchKernelGGL(k_logits, dim3(1), dim3(640), 0, stream, part, rinv, cw, cb, out);
}